// Round 2
// baseline (3308.434 us; speedup 1.0000x reference)
//
#include <hip/hip_runtime.h>
#include <hip/hip_bf16.h>

// Problem: B=8, N=2048, D=1024, ATT=128   (all I/O float32)
//   f = x@Wf + bf ; g = x@Wg + bg            [B,N,128]
//   att = softmax(f @ g^T, axis=-1)          [B,N,N] (never materialized)
//   out = att @ x + x                        [B,N,1024]

#define B_ 8
#define N_ 2048
#define D_ 1024
#define A_ 128

using bf16 = __hip_bfloat16;

// unpack 2 bf16 (packed in a u32) -> 2 floats
__device__ __forceinline__ float2 bfpair(unsigned int u) {
    union { unsigned int a; float f; } lo, hi;
    lo.a = u << 16;
    hi.a = u & 0xffff0000u;
    float2 r; r.x = lo.f; r.y = hi.f; return r;
}

// ---------------------------------------------------------------------------
// Kernel 1: f = x@Wf + bf, g = x@Wg + bg   (fp32 -> fp32 workspace)
// grid: B*N/8 blocks, 128 threads. Block: 8 rows; thread a owns column a.
// x staged TRANSPOSED in LDS (xs[d][r], stride 8): main loop does 2 broadcast
// ds_read_b128 per d (no conflicts); staging scatter-writes conflict but run
// only 16 iterations (negligible vs the 1024-iteration main loop).
// ---------------------------------------------------------------------------
__global__ __launch_bounds__(128) void fg_kernel(
    const float* __restrict__ x, const float* __restrict__ Wf, const float* __restrict__ bfv,
    const float* __restrict__ Wg, const float* __restrict__ bgv,
    float* __restrict__ f, float* __restrict__ g)
{
    __shared__ __align__(16) float xs[D_ * 8];   // 32 KB, transposed [d][r]
    const int row0 = blockIdx.x * 8;
    const int tid  = threadIdx.x;

    for (int idx4 = tid; idx4 < 8 * (D_ / 4); idx4 += 128) {
        int r  = idx4 >> 8;            // 0..7   (D_/4 = 256 float4 per row)
        int d4 = idx4 & 255;
        float4 v = ((const float4*)(x + (size_t)(row0 + r) * D_))[d4];
        int d = d4 * 4;
        xs[(d + 0) * 8 + r] = v.x;
        xs[(d + 1) * 8 + r] = v.y;
        xs[(d + 2) * 8 + r] = v.z;
        xs[(d + 3) * 8 + r] = v.w;
    }
    __syncthreads();

    const int a = tid;                // 0..127 output column
    float fa[8], ga[8];
#pragma unroll
    for (int r = 0; r < 8; ++r) { fa[r] = 0.f; ga[r] = 0.f; }

    for (int d = 0; d < D_; ++d) {
        float wf = Wf[d * A_ + a];    // coalesced 4B loads, L2-resident
        float wg = Wg[d * A_ + a];
        float xv[8];
        *(float4*)&xv[0] = *(const float4*)&xs[d * 8];      // broadcast b128
        *(float4*)&xv[4] = *(const float4*)&xs[d * 8 + 4];
#pragma unroll
        for (int r = 0; r < 8; ++r) {
            fa[r] = fmaf(xv[r], wf, fa[r]);
            ga[r] = fmaf(xv[r], wg, ga[r]);
        }
    }
    const float fb = bfv[a];
    const float gb = bgv[a];
#pragma unroll
    for (int r = 0; r < 8; ++r) {
        f[(size_t)(row0 + r) * A_ + a] = fa[r] + fb;
        g[(size_t)(row0 + r) * A_ + a] = ga[r] + gb;
    }
}

// ---------------------------------------------------------------------------
// Kernel 2: flash attention + PV + residual, fp32 out.
// Block = (d_chunk of 256, n-tile of 32 rows, batch). 256 threads.
// Thread t: row i = t>>3 (0..31), lane-in-row l8 = t&7.
//   logits: j = l8 + 8*jj (jj=0..3) -> row reductions via shfl_xor 1,2,4.
//   acc:    32 fp32 = d values l8*4 + 32*q + c (q=0..7, c=0..3).
// LDS: fs/gs fp32 stride 132 (bank-safe float4); x tile stored as BF16
// (converted at staging; keeps total LDS at 54.4 KB < 64 KB; PV rel err
// ~2^-9 << 2% threshold). Residual uses global fp32 x directly.
// ---------------------------------------------------------------------------
#define TN 32
#define TM 32
#define TD 256
#define FSS 132
#define PSS 33

__global__ __launch_bounds__(256) void attn_kernel(
    const float* __restrict__ x, const float* __restrict__ f, const float* __restrict__ g,
    float* __restrict__ out)
{
    __shared__ __align__(16) float fs[TN * FSS];
    __shared__ __align__(16) float gs[TM * FSS];
    __shared__ __align__(16) bf16  xsh[TM * TD];
    __shared__ __align__(16) float pS[TN * PSS];

    const int dch = blockIdx.x;        // 0..3
    const int nt  = blockIdx.y;        // 0..63
    const int b   = blockIdx.z;        // 0..7
    const int n0 = nt * TN;
    const int d0 = dch * TD;
    const int tid = threadIdx.x;
    const int i   = tid >> 3;          // 0..31
    const int l8  = tid & 7;           // 0..7

    // stage f rows for this n-tile (fp32 float4)
    for (int idx4 = tid; idx4 < TN * (A_ / 4); idx4 += 256) {
        int r = idx4 >> 5, a4 = idx4 & 31;
        *(float4*)&fs[r * FSS + a4 * 4] =
            ((const float4*)(f + (size_t)(b * N_ + n0 + r) * A_))[a4];
    }

    float acc[32];
#pragma unroll
    for (int q = 0; q < 32; ++q) acc[q] = 0.f;
    float m_i = -3.0e38f, l_i = 0.f;

    for (int m0 = 0; m0 < N_; m0 += TM) {
        __syncthreads();   // protect LDS from previous iteration's readers
        // stage g tile (fp32)
        for (int idx4 = tid; idx4 < TM * (A_ / 4); idx4 += 256) {
            int r = idx4 >> 5, a4 = idx4 & 31;
            *(float4*)&gs[r * FSS + a4 * 4] =
                ((const float4*)(g + (size_t)(b * N_ + m0 + r) * A_))[a4];
        }
        // stage x tile: fp32 global -> bf16 LDS (4 elems per thread-iter)
        for (int idx4 = tid; idx4 < TM * (TD / 4); idx4 += 256) {
            int r = idx4 >> 6, c4 = idx4 & 63;        // TD/4 = 64
            float4 v = ((const float4*)(x + (size_t)(b * N_ + m0 + r) * D_ + d0))[c4];
            union { bf16 h[4]; uint2 u; } pk;
            pk.h[0] = __float2bfloat16(v.x);
            pk.h[1] = __float2bfloat16(v.y);
            pk.h[2] = __float2bfloat16(v.z);
            pk.h[3] = __float2bfloat16(v.w);
            ((uint2*)(xsh + r * TD))[c4] = pk.u;
        }
        __syncthreads();

        // ---- logits s[i][j], j = l8 + 8*jj ----
        float s0 = 0.f, s1 = 0.f, s2 = 0.f, s3 = 0.f;
        const float4* f4 = (const float4*)(fs + i * FSS);
        const float4* g0 = (const float4*)(gs + (l8     ) * FSS);
        const float4* g1 = (const float4*)(gs + (l8 +  8) * FSS);
        const float4* g2 = (const float4*)(gs + (l8 + 16) * FSS);
        const float4* g3 = (const float4*)(gs + (l8 + 24) * FSS);
#pragma unroll 2
        for (int a4 = 0; a4 < A_ / 4; ++a4) {
            float4 fv = f4[a4];
            float4 v0 = g0[a4], v1 = g1[a4], v2 = g2[a4], v3 = g3[a4];
            s0 = fmaf(fv.x, v0.x, s0); s0 = fmaf(fv.y, v0.y, s0);
            s0 = fmaf(fv.z, v0.z, s0); s0 = fmaf(fv.w, v0.w, s0);
            s1 = fmaf(fv.x, v1.x, s1); s1 = fmaf(fv.y, v1.y, s1);
            s1 = fmaf(fv.z, v1.z, s1); s1 = fmaf(fv.w, v1.w, s1);
            s2 = fmaf(fv.x, v2.x, s2); s2 = fmaf(fv.y, v2.y, s2);
            s2 = fmaf(fv.z, v2.z, s2); s2 = fmaf(fv.w, v2.w, s2);
            s3 = fmaf(fv.x, v3.x, s3); s3 = fmaf(fv.y, v3.y, s3);
            s3 = fmaf(fv.z, v3.z, s3); s3 = fmaf(fv.w, v3.w, s3);
        }

        // ---- online softmax (row = 8 lanes, shfl within wave) ----
        float smax = fmaxf(fmaxf(s0, s1), fmaxf(s2, s3));
        smax = fmaxf(smax, __shfl_xor(smax, 1));
        smax = fmaxf(smax, __shfl_xor(smax, 2));
        smax = fmaxf(smax, __shfl_xor(smax, 4));
        float mnew  = fmaxf(m_i, smax);
        float alpha = __expf(m_i - mnew);        // first tile: exp(-huge)=0
        s0 = __expf(s0 - mnew); s1 = __expf(s1 - mnew);
        s2 = __expf(s2 - mnew); s3 = __expf(s3 - mnew);
        float rsum = s0 + s1 + s2 + s3;
        rsum += __shfl_xor(rsum, 1);
        rsum += __shfl_xor(rsum, 2);
        rsum += __shfl_xor(rsum, 4);
        l_i = l_i * alpha + rsum;
        m_i = mnew;
#pragma unroll
        for (int q = 0; q < 32; ++q) acc[q] *= alpha;

        pS[i * PSS + l8     ] = s0;
        pS[i * PSS + l8 +  8] = s1;
        pS[i * PSS + l8 + 16] = s2;
        pS[i * PSS + l8 + 24] = s3;
        __syncthreads();

        // ---- PV: acc[d] += p[i][j] * x_bf16[m0+j][d0+d] ----
        for (int j = 0; j < TM; ++j) {
            float pv = pS[i * PSS + j];
            const uint2* xr = (const uint2*)(xsh + j * TD);
#pragma unroll
            for (int q = 0; q < 8; ++q) {
                uint2 v = xr[l8 + 8 * q];     // 4 bf16, d = l8*4 + 32q .. +3
                float2 ab = bfpair(v.x);
                float2 cd = bfpair(v.y);
                acc[q * 4 + 0] = fmaf(pv, ab.x, acc[q * 4 + 0]);
                acc[q * 4 + 1] = fmaf(pv, ab.y, acc[q * 4 + 1]);
                acc[q * 4 + 2] = fmaf(pv, cd.x, acc[q * 4 + 2]);
                acc[q * 4 + 3] = fmaf(pv, cd.y, acc[q * 4 + 3]);
            }
        }
    }

    // ---- epilogue: normalize, residual (fp32 x from global), fp32 store ----
    const float inv = 1.0f / l_i;
    const size_t rowbase = (size_t)(b * N_ + n0 + i) * D_ + d0;
    const float4* xres = (const float4*)(x + rowbase);
    float4* orow = (float4*)(out + rowbase);
#pragma unroll
    for (int q = 0; q < 8; ++q) {
        float4 xv = xres[l8 + 8 * q];
        float4 r;
        r.x = fmaf(acc[q * 4 + 0], inv, xv.x);
        r.y = fmaf(acc[q * 4 + 1], inv, xv.y);
        r.z = fmaf(acc[q * 4 + 2], inv, xv.z);
        r.w = fmaf(acc[q * 4 + 3], inv, xv.w);
        orow[l8 + 8 * q] = r;
    }
}

extern "C" void kernel_launch(void* const* d_in, const int* in_sizes, int n_in,
                              void* d_out, int out_size, void* d_ws, size_t ws_size,
                              hipStream_t stream) {
    const float* x   = (const float*)d_in[0];
    const float* Wf  = (const float*)d_in[1];
    const float* bfv = (const float*)d_in[2];
    const float* Wg  = (const float*)d_in[3];
    const float* bgv = (const float*)d_in[4];
    float* out = (float*)d_out;

    // workspace: f, g fp32 [B*N, 128] = 8 MB each; fully overwritten by
    // fg_kernel before attn_kernel reads (same stream => ordered)
    float* f = (float*)d_ws;
    float* g = f + (size_t)B_ * N_ * A_;

    hipLaunchKernelGGL(fg_kernel, dim3(B_ * N_ / 8), dim3(128), 0, stream,
                       x, Wf, bfv, Wg, bgv, f, g);
    hipLaunchKernelGGL(attn_kernel, dim3(D_ / TD, N_ / TN, B_), dim3(256), 0, stream,
                       x, f, g, out);
}

// Round 4
// 539.299 us; speedup vs baseline: 6.1347x; 6.1347x over previous
//
#include <hip/hip_runtime.h>
#include <hip/hip_fp16.h>

// Problem: B=8, N=2048, D=1024, ATT=128   (all I/O float32)
//   f = x@Wf + bf ; g = x@Wg + bg ; out = softmax(f g^T) @ x + x
// Round 4 = round 3 with the host-pass compile fix: MFMA builtins are wrapped
// in __HIP_DEVICE_COMPILE__ (host pass parses device fns but lacks the
// builtins; round 3's #if __has_builtin chain #error'd on host).
// Key trick: compute S^T = g.f^T with mfma_f32_16x16x32_f16 -> its C-layout
// (col=lane&15=i, row=quad*4+reg=j) IS the A-layout of mfma_f32_16x16x16f16
// (m=lane&15, k=quad*4+reg), so exp(S)->P feeds PV entirely in registers.

#define B_ 8
#define N_ 2048
#define D_ 1024
#define A_ 128

typedef _Float16 half8v  __attribute__((ext_vector_type(8)));
typedef _Float16 half4v  __attribute__((ext_vector_type(4)));
typedef float    floatx4 __attribute__((ext_vector_type(4)));

__device__ __forceinline__ floatx4 mfma_qk(half8v a, half8v b, floatx4 c) {
#if defined(__HIP_DEVICE_COMPILE__)
    return __builtin_amdgcn_mfma_f32_16x16x32_f16(a, b, c, 0, 0, 0);
#else
    return c;   // host pass: never executed
#endif
}
__device__ __forceinline__ floatx4 mfma_pv(half4v a, half4v b, floatx4 c) {
#if defined(__HIP_DEVICE_COMPILE__)
    return __builtin_amdgcn_mfma_f32_16x16x16f16(a, b, c, 0, 0, 0);
#else
    return c;   // host pass: never executed
#endif
}

// ---------------------------------------------------------------------------
// Kernel 0: transpose+convert x [b][n][d] fp32 -> xT [b][d][n] f16.
// 64x64 tiles via LDS (stride 80 halves = 160B, 16B-aligned rows).
// ---------------------------------------------------------------------------
__global__ __launch_bounds__(256) void xpose_kernel(
    const float* __restrict__ x, _Float16* __restrict__ xT)
{
    __shared__ __align__(16) _Float16 ts[64][80];
    const int n0 = blockIdx.x * 64, d0 = blockIdx.y * 64, b = blockIdx.z;
    const int t = threadIdx.x;
#pragma unroll
    for (int s = 0; s < 4; ++s) {
        int idx = t + 256 * s;
        int nl = idx >> 4, c4 = idx & 15;
        float4 v = ((const float4*)(x + ((size_t)(b * N_ + n0 + nl)) * D_ + d0))[c4];
        ts[c4 * 4 + 0][nl] = (_Float16)v.x;
        ts[c4 * 4 + 1][nl] = (_Float16)v.y;
        ts[c4 * 4 + 2][nl] = (_Float16)v.z;
        ts[c4 * 4 + 3][nl] = (_Float16)v.w;
    }
    __syncthreads();
#pragma unroll
    for (int s = 0; s < 2; ++s) {
        int idx = t + 256 * s;
        int dl = idx >> 3, c = idx & 7;
        *(uint4*)&xT[((size_t)b * D_ + d0 + dl) * N_ + n0 + c * 8] =
            *(const uint4*)&ts[dl][c * 8];
    }
}

// ---------------------------------------------------------------------------
// Kernel 1: f = x@Wf + bf, g = x@Wg + bg  (fp32 math, f16 stores)
// ---------------------------------------------------------------------------
__global__ __launch_bounds__(128) void fg_kernel(
    const float* __restrict__ x, const float* __restrict__ Wf, const float* __restrict__ bfv,
    const float* __restrict__ Wg, const float* __restrict__ bgv,
    _Float16* __restrict__ f, _Float16* __restrict__ g)
{
    __shared__ __align__(16) float xs[D_ * 8];   // transposed [d][r]
    const int row0 = blockIdx.x * 8;
    const int tid  = threadIdx.x;

    for (int idx4 = tid; idx4 < 8 * (D_ / 4); idx4 += 128) {
        int r  = idx4 >> 8;
        int d4 = idx4 & 255;
        float4 v = ((const float4*)(x + (size_t)(row0 + r) * D_))[d4];
        int d = d4 * 4;
        xs[(d + 0) * 8 + r] = v.x;
        xs[(d + 1) * 8 + r] = v.y;
        xs[(d + 2) * 8 + r] = v.z;
        xs[(d + 3) * 8 + r] = v.w;
    }
    __syncthreads();

    const int a = tid;
    float fa[8], ga[8];
#pragma unroll
    for (int r = 0; r < 8; ++r) { fa[r] = 0.f; ga[r] = 0.f; }

    for (int d = 0; d < D_; ++d) {
        float wf = Wf[d * A_ + a];
        float wg = Wg[d * A_ + a];
        float xv[8];
        *(float4*)&xv[0] = *(const float4*)&xs[d * 8];
        *(float4*)&xv[4] = *(const float4*)&xs[d * 8 + 4];
#pragma unroll
        for (int r = 0; r < 8; ++r) {
            fa[r] = fmaf(xv[r], wf, fa[r]);
            ga[r] = fmaf(xv[r], wg, ga[r]);
        }
    }
    const float fb = bfv[a];
    const float gb = bgv[a];
#pragma unroll
    for (int r = 0; r < 8; ++r) {
        f[(size_t)(row0 + r) * A_ + a] = (_Float16)(fa[r] + fb);
        g[(size_t)(row0 + r) * A_ + a] = (_Float16)(ga[r] + gb);
    }
}

// ---------------------------------------------------------------------------
// Kernel 2: MFMA flash attention.
// Block: 256 thr = 4 waves; 128 queries (32/wave, 2 i-tiles) x 256 d-cols.
// Grid: (D/256=4, N/128=16, B=8) = 512 blocks = exactly 2/CU resident.
// Per k-iter (32 keys): stage g[32][128], xT[256][32] in LDS;
//   QK: 16x mfma_16x16x32_f16 (A=g rows, B=f rows preloaded in regs);
//   softmax: in-lane + cross-half shfl reductions, state per i=lane&15;
//   PV: 64x mfma_16x16x16f16, A=P in-register, B=xT tile (b64 reads).
// ---------------------------------------------------------------------------
__global__ __launch_bounds__(256, 2) void attn_kernel(
    const float* __restrict__ x, const _Float16* __restrict__ f,
    const _Float16* __restrict__ g, const _Float16* __restrict__ xT,
    float* __restrict__ out)
{
    __shared__ __align__(16) _Float16 gS[32 * 136];    // pad: stride 136 halves
    __shared__ __align__(16) _Float16 xTs[256 * 36];   // pad: stride 36 halves

    const int dch = blockIdx.x;
    const int nt  = blockIdx.y;
    const int b   = blockIdx.z;
    const int tid = threadIdx.x;
    const int wave = tid >> 6, lane = tid & 63;
    const int quad = lane >> 4, l16 = lane & 15;
    const int d0 = dch * 256;
    const int qbase = nt * 128 + wave * 32;

    // preload f B-frags: fb[it][kc], B[k=att][n=query]: n=l16, k=quad*8+j
    half8v fb[2][4];
#pragma unroll
    for (int it = 0; it < 2; ++it)
#pragma unroll
        for (int kc = 0; kc < 4; ++kc)
            fb[it][kc] = *(const half8v*)(f +
                ((size_t)(b * N_ + qbase + it * 16 + l16)) * A_ + kc * 32 + quad * 8);

    floatx4 acc[2][16];
#pragma unroll
    for (int it = 0; it < 2; ++it)
#pragma unroll
        for (int dt = 0; dt < 16; ++dt)
            acc[it][dt] = (floatx4){0.f, 0.f, 0.f, 0.f};
    float m_i[2] = {-3.0e38f, -3.0e38f};
    float l_i[2] = {0.f, 0.f};

    for (int m0 = 0; m0 < N_; m0 += 32) {
        __syncthreads();
        // stage g tile: 32 rows x 128 halves (512 uint4)
#pragma unroll
        for (int s = 0; s < 2; ++s) {
            int idx = tid + 256 * s;
            int r = idx >> 4, c = idx & 15;
            *(uint4*)&gS[r * 136 + c * 8] =
                *(const uint4*)(g + ((size_t)(b * N_ + m0 + r)) * A_ + c * 8);
        }
        // stage xT tile: 256 d-rows x 32 halves (2048 uint2)
#pragma unroll
        for (int s = 0; s < 8; ++s) {
            int idx = tid + 256 * s;
            int rr = idx >> 3, c = idx & 7;
            *(uint2*)&xTs[rr * 36 + c * 4] =
                *(const uint2*)(xT + ((size_t)b * D_ + d0 + rr) * N_ + m0 + c * 4);
        }
        __syncthreads();

        // ---- QK: S^T[j][i], A=g (m=j), B=f (n=i) ----
        floatx4 sc[2][2];
#pragma unroll
        for (int jt = 0; jt < 2; ++jt)
#pragma unroll
            for (int it = 0; it < 2; ++it)
                sc[jt][it] = (floatx4){0.f, 0.f, 0.f, 0.f};
#pragma unroll
        for (int kc = 0; kc < 4; ++kc) {
            half8v ga0 = *(const half8v*)&gS[(l16     ) * 136 + kc * 32 + quad * 8];
            half8v ga1 = *(const half8v*)&gS[(l16 + 16) * 136 + kc * 32 + quad * 8];
            sc[0][0] = mfma_qk(ga0, fb[0][kc], sc[0][0]);
            sc[0][1] = mfma_qk(ga0, fb[1][kc], sc[0][1]);
            sc[1][0] = mfma_qk(ga1, fb[0][kc], sc[1][0]);
            sc[1][1] = mfma_qk(ga1, fb[1][kc], sc[1][1]);
        }

        // ---- online softmax; per-lane state for query i = l16 (per i-tile) ----
        float alpha[2];
        half4v pa[2][2];     // pa[jt][it]: A-frag K=16 (k = quad*4 + reg)
        bool need = false;
#pragma unroll
        for (int it = 0; it < 2; ++it) {
            float t0 = fmaxf(fmaxf(sc[0][it][0], sc[0][it][1]),
                             fmaxf(sc[0][it][2], sc[0][it][3]));
            float t1 = fmaxf(fmaxf(sc[1][it][0], sc[1][it][1]),
                             fmaxf(sc[1][it][2], sc[1][it][3]));
            float tm = fmaxf(t0, t1);
            tm = fmaxf(tm, __shfl_xor(tm, 16));
            tm = fmaxf(tm, __shfl_xor(tm, 32));
            need = need || (tm > m_i[it]);
            float mnew = fmaxf(m_i[it], tm);
            alpha[it] = __expf(m_i[it] - mnew);
            float rs = 0.f;
#pragma unroll
            for (int jt = 0; jt < 2; ++jt) {
                float p0 = __expf(sc[jt][it][0] - mnew);
                float p1 = __expf(sc[jt][it][1] - mnew);
                float p2 = __expf(sc[jt][it][2] - mnew);
                float p3 = __expf(sc[jt][it][3] - mnew);
                rs += (p0 + p1) + (p2 + p3);
                pa[jt][it] = (half4v){(_Float16)p0, (_Float16)p1,
                                      (_Float16)p2, (_Float16)p3};
            }
            rs += __shfl_xor(rs, 16);
            rs += __shfl_xor(rs, 32);
            l_i[it] = l_i[it] * alpha[it] + rs;
            m_i[it] = mnew;
        }

        // rescale acc only when some row's max moved (wave-uniform branch)
        if (__any(need)) {
            float ar[2][4];
#pragma unroll
            for (int it = 0; it < 2; ++it)
#pragma unroll
                for (int r = 0; r < 4; ++r)
                    ar[it][r] = __shfl(alpha[it], quad * 4 + r);
#pragma unroll
            for (int it = 0; it < 2; ++it)
#pragma unroll
                for (int dt = 0; dt < 16; ++dt)
#pragma unroll
                    for (int r = 0; r < 4; ++r)
                        acc[it][dt][r] *= ar[it][r];
        }

        // ---- PV: O[i][d] += P[i][j] x[j][d]; B from xTs (n=l16=d, k=quad*4+j)
#pragma unroll
        for (int dt = 0; dt < 16; ++dt) {
            const int rowoff = (dt * 16 + l16) * 36;
            half4v xb0 = *(const half4v*)&xTs[rowoff + quad * 4];
            half4v xb1 = *(const half4v*)&xTs[rowoff + 16 + quad * 4];
            acc[0][dt] = mfma_pv(pa[0][0], xb0, acc[0][dt]);
            acc[0][dt] = mfma_pv(pa[1][0], xb1, acc[0][dt]);
            acc[1][dt] = mfma_pv(pa[0][1], xb0, acc[1][dt]);
            acc[1][dt] = mfma_pv(pa[1][1], xb1, acc[1][dt]);
        }
    }

    // ---- epilogue: normalize (l in i=l16 layout -> shfl), residual, store ----
    float linv[2][4];
#pragma unroll
    for (int it = 0; it < 2; ++it)
#pragma unroll
        for (int r = 0; r < 4; ++r)
            linv[it][r] = 1.0f / __shfl(l_i[it], quad * 4 + r);

#pragma unroll
    for (int it = 0; it < 2; ++it)
#pragma unroll
        for (int r = 0; r < 4; ++r) {
            const size_t rowoff =
                ((size_t)(b * N_ + qbase + it * 16 + quad * 4 + r)) * D_ + d0;
#pragma unroll
            for (int dt = 0; dt < 16; ++dt) {
                int col = dt * 16 + l16;
                out[rowoff + col] = fmaf(acc[it][dt][r], linv[it][r], x[rowoff + col]);
            }
        }
}

extern "C" void kernel_launch(void* const* d_in, const int* in_sizes, int n_in,
                              void* d_out, int out_size, void* d_ws, size_t ws_size,
                              hipStream_t stream) {
    const float* x   = (const float*)d_in[0];
    const float* Wf  = (const float*)d_in[1];
    const float* bfv = (const float*)d_in[2];
    const float* Wg  = (const float*)d_in[3];
    const float* bgv = (const float*)d_in[4];
    float* out = (float*)d_out;

    // ws layout (all fully rewritten every call):
    //   [0,4MB)   f  f16 [B*N][128]
    //   [4,8MB)   g  f16 [B*N][128]
    //   [8,41.9MB) xT f16 [B][D][N]
    _Float16* fh = (_Float16*)d_ws;
    _Float16* gh = fh + (size_t)B_ * N_ * A_;
    _Float16* xT = gh + (size_t)B_ * N_ * A_;

    hipLaunchKernelGGL(xpose_kernel, dim3(N_ / 64, D_ / 64, B_), dim3(256), 0, stream,
                       x, xT);
    hipLaunchKernelGGL(fg_kernel, dim3(B_ * N_ / 8), dim3(128), 0, stream,
                       x, Wf, bfv, Wg, bgv, fh, gh);
    hipLaunchKernelGGL(attn_kernel, dim3(D_ / 256, N_ / 128, B_), dim3(256), 0, stream,
                       x, fh, gh, xT, out);
}

// Round 5
// 350.594 us; speedup vs baseline: 9.4366x; 1.5382x over previous
//
#include <hip/hip_runtime.h>
#include <hip/hip_fp16.h>

// Problem: B=8, N=2048, D=1024, ATT=128   (all I/O float32)
//   f = x@Wf + bf ; g = x@Wg + bg ; out = softmax(f g^T) @ x + x
// Round 5: fg moves to MFMA (was 262us scalar, latency-bound w/ 64-way LDS
// write conflicts); attn gets register-prefetch staging, b128 PV frag reads
// via permuted xTs rows, and lazy softmax rescale (slack 8).

#define B_ 8
#define N_ 2048
#define D_ 1024
#define A_ 128

typedef _Float16 half8v  __attribute__((ext_vector_type(8)));
typedef _Float16 half4v  __attribute__((ext_vector_type(4)));
typedef float    floatx4 __attribute__((ext_vector_type(4)));

__device__ __forceinline__ floatx4 mfma_16x16x32(half8v a, half8v b, floatx4 c) {
#if defined(__HIP_DEVICE_COMPILE__)
    return __builtin_amdgcn_mfma_f32_16x16x32_f16(a, b, c, 0, 0, 0);
#else
    return c;
#endif
}
__device__ __forceinline__ floatx4 mfma_16x16x16(half4v a, half4v b, floatx4 c) {
#if defined(__HIP_DEVICE_COMPILE__)
    return __builtin_amdgcn_mfma_f32_16x16x16f16(a, b, c, 0, 0, 0);
#else
    return c;
#endif
}

// ---------------------------------------------------------------------------
// Kernel 0: transpose+convert x [b][n][d] fp32 -> xT [b][d][n] f16.
// ---------------------------------------------------------------------------
__global__ __launch_bounds__(256) void xpose_kernel(
    const float* __restrict__ x, _Float16* __restrict__ xT)
{
    __shared__ __align__(16) _Float16 ts[64][80];
    const int n0 = blockIdx.x * 64, d0 = blockIdx.y * 64, b = blockIdx.z;
    const int t = threadIdx.x;
#pragma unroll
    for (int s = 0; s < 4; ++s) {
        int idx = t + 256 * s;
        int nl = idx >> 4, c4 = idx & 15;
        float4 v = ((const float4*)(x + ((size_t)(b * N_ + n0 + nl)) * D_ + d0))[c4];
        ts[c4 * 4 + 0][nl] = (_Float16)v.x;
        ts[c4 * 4 + 1][nl] = (_Float16)v.y;
        ts[c4 * 4 + 2][nl] = (_Float16)v.z;
        ts[c4 * 4 + 3][nl] = (_Float16)v.w;
    }
    __syncthreads();
#pragma unroll
    for (int s = 0; s < 2; ++s) {
        int idx = t + 256 * s;
        int dl = idx >> 3, c = idx & 7;
        *(uint4*)&xT[((size_t)b * D_ + d0 + dl) * N_ + n0 + c * 8] =
            *(const uint4*)&ts[dl][c * 8];
    }
}

// ---------------------------------------------------------------------------
// Kernel 0b: W [1024][128] f32 -> whT [2][128][1024] f16 (transposed, K-major)
// ---------------------------------------------------------------------------
__global__ __launch_bounds__(256) void wprep_kernel(
    const float* __restrict__ Wf, const float* __restrict__ Wg,
    _Float16* __restrict__ whT)
{
    __shared__ __align__(16) _Float16 ts[64][72];
    const int k0 = blockIdx.x * 64, c0 = blockIdx.y * 64;
    const float* W = blockIdx.z ? Wg : Wf;
    _Float16* dst = whT + (size_t)blockIdx.z * A_ * D_;
    const int t = threadIdx.x;
#pragma unroll
    for (int s = 0; s < 4; ++s) {
        int idx = t + 256 * s;
        int kl = idx >> 4, c4 = idx & 15;
        float4 v = *(const float4*)&W[(size_t)(k0 + kl) * A_ + c0 + c4 * 4];
        ts[c4 * 4 + 0][kl] = (_Float16)v.x;
        ts[c4 * 4 + 1][kl] = (_Float16)v.y;
        ts[c4 * 4 + 2][kl] = (_Float16)v.z;
        ts[c4 * 4 + 3][kl] = (_Float16)v.w;
    }
    __syncthreads();
#pragma unroll
    for (int s = 0; s < 2; ++s) {
        int idx = t + 256 * s;
        int cl = idx >> 3, ch = idx & 7;
        *(uint4*)&dst[(size_t)(c0 + cl) * D_ + k0 + ch * 8] =
            *(const uint4*)&ts[cl][ch * 8];
    }
}

// ---------------------------------------------------------------------------
// Kernel 1: MFMA GEMM  fh|gh = (f16)(x @ W + b).  Grid (2, M/64): bx selects
// Wf or Wg (x re-read hits L3). Block 64 rows x 128 cols, 4 waves in 2x2;
// wave: 32 rows x 64 cols (acc 32 f32/lane). K-loop 32x32 with register
// prefetch; LDS stride 48 halves (2-way conflicts only = free).
// ---------------------------------------------------------------------------
__global__ __launch_bounds__(256) void fgmm_kernel(
    const float* __restrict__ x, const _Float16* __restrict__ whT,
    const float* __restrict__ bfv, const float* __restrict__ bgv,
    _Float16* __restrict__ fh, _Float16* __restrict__ gh)
{
    __shared__ __align__(16) _Float16 xs[64 * 48];
    __shared__ __align__(16) _Float16 wt[128 * 48];
    const int colh = blockIdx.x;             // 0 = f, 1 = g
    const int row0 = blockIdx.y * 64;
    const int t = threadIdx.x;
    const int w = t >> 6, lane = t & 63, quad = lane >> 4, l16 = lane & 15;
    const int mtb = (w >> 1) * 32;           // wave row base within tile
    const int wc  = (w & 1) * 64;            // wave col base within tile

    float4 xR[2];
    uint4  wR[2];
#define FG_LOAD_TILE(K0)                                                      \
    {                                                                         \
        _Pragma("unroll")                                                     \
        for (int s = 0; s < 2; ++s) {                                         \
            int idx = t + 256 * s;                                            \
            int r = idx >> 3, c8 = idx & 7;                                   \
            xR[s] = *(const float4*)&x[(size_t)(row0 + r) * D_ + (K0) + c8 * 4]; \
        }                                                                     \
        _Pragma("unroll")                                                     \
        for (int s = 0; s < 2; ++s) {                                         \
            int idx = t + 256 * s;                                            \
            int c = idx >> 2, q = idx & 3;                                    \
            wR[s] = *(const uint4*)&whT[((size_t)(colh * A_ + c)) * D_ + (K0) + q * 8]; \
        }                                                                     \
    }

    FG_LOAD_TILE(0)

    floatx4 acc[2][4];
#pragma unroll
    for (int ms = 0; ms < 2; ++ms)
#pragma unroll
        for (int nt = 0; nt < 4; ++nt)
            acc[ms][nt] = (floatx4){0.f, 0.f, 0.f, 0.f};

    for (int kt = 0; kt < 32; ++kt) {
        __syncthreads();
#pragma unroll
        for (int s = 0; s < 2; ++s) {
            int idx = t + 256 * s;
            int r = idx >> 3, c8 = idx & 7;
            half4v h = {(_Float16)xR[s].x, (_Float16)xR[s].y,
                        (_Float16)xR[s].z, (_Float16)xR[s].w};
            *(half4v*)&xs[r * 48 + c8 * 4] = h;
        }
#pragma unroll
        for (int s = 0; s < 2; ++s) {
            int idx = t + 256 * s;
            int c = idx >> 2, q = idx & 3;
            *(uint4*)&wt[c * 48 + q * 8] = wR[s];
        }
        __syncthreads();
        if (kt < 31) FG_LOAD_TILE((kt + 1) * 32)

        half8v a0 = *(const half8v*)&xs[(mtb + l16) * 48 + quad * 8];
        half8v a1 = *(const half8v*)&xs[(mtb + 16 + l16) * 48 + quad * 8];
#pragma unroll
        for (int nt = 0; nt < 4; ++nt) {
            half8v bfr = *(const half8v*)&wt[(wc + nt * 16 + l16) * 48 + quad * 8];
            acc[0][nt] = mfma_16x16x32(a0, bfr, acc[0][nt]);
            acc[1][nt] = mfma_16x16x32(a1, bfr, acc[1][nt]);
        }
    }

    _Float16* dst = colh ? gh : fh;
    const float* bias = colh ? bgv : bfv;
#pragma unroll
    for (int nt = 0; nt < 4; ++nt) {
        int col = wc + nt * 16 + l16;
        float bv = bias[col];
#pragma unroll
        for (int ms = 0; ms < 2; ++ms)
#pragma unroll
            for (int rg = 0; rg < 4; ++rg) {
                int row = row0 + mtb + ms * 16 + quad * 4 + rg;
                dst[(size_t)row * A_ + col] = (_Float16)(acc[ms][nt][rg] + bv);
            }
    }
}

// ---------------------------------------------------------------------------
// Kernel 2: MFMA flash attention (round-4 verified layouts + 3 upgrades):
//  - register-prefetch staging (loads in flight across the compute phase)
//  - xTs rows permuted at 8B granularity so each PV A/B frag pair is ONE
//    ds_read_b128 (stride 40 halves: 16B-aligned, conflict-free)
//  - lazy rescale: only when a row max moves by >8 (P<=e^8 fits f16)
// ---------------------------------------------------------------------------
__global__ __launch_bounds__(256, 2) void attn_kernel(
    const float* __restrict__ x, const _Float16* __restrict__ f,
    const _Float16* __restrict__ g, const _Float16* __restrict__ xT,
    float* __restrict__ out)
{
    __shared__ __align__(16) _Float16 gS[32 * 136];
    __shared__ __align__(16) _Float16 xTs[256 * 40];

    const int dch = blockIdx.x;
    const int nt  = blockIdx.y;
    const int b   = blockIdx.z;
    const int tid = threadIdx.x;
    const int wave = tid >> 6, lane = tid & 63;
    const int quad = lane >> 4, l16 = lane & 15;
    const int d0 = dch * 256;
    const int qbase = nt * 128 + wave * 32;

    // f B-frags in regs: B[k=att][n=query]: n=l16, k=quad*8+j
    half8v fb[2][4];
#pragma unroll
    for (int it = 0; it < 2; ++it)
#pragma unroll
        for (int kc = 0; kc < 4; ++kc)
            fb[it][kc] = *(const half8v*)(f +
                ((size_t)(b * N_ + qbase + it * 16 + l16)) * A_ + kc * 32 + quad * 8);

    uint4 gR[2];
    uint2 xR[8];
#define AT_LOAD_TILE(M0)                                                      \
    {                                                                         \
        _Pragma("unroll")                                                     \
        for (int s = 0; s < 2; ++s) {                                         \
            int idx = tid + 256 * s;                                          \
            int r = idx >> 4, c = idx & 15;                                   \
            gR[s] = *(const uint4*)(g + ((size_t)(b * N_ + (M0) + r)) * A_ + c * 8); \
        }                                                                     \
        _Pragma("unroll")                                                     \
        for (int s = 0; s < 8; ++s) {                                         \
            int idx = tid + 256 * s;                                          \
            int rr = idx >> 3, p = idx & 7;                                   \
            int kp = ((p & 1) << 4) + (p >> 1) * 4;                           \
            xR[s] = *(const uint2*)(xT + ((size_t)b * D_ + d0 + rr) * N_ + (M0) + kp); \
        }                                                                     \
    }

    AT_LOAD_TILE(0)

    floatx4 acc[2][16];
#pragma unroll
    for (int it = 0; it < 2; ++it)
#pragma unroll
        for (int dt = 0; dt < 16; ++dt)
            acc[it][dt] = (floatx4){0.f, 0.f, 0.f, 0.f};
    float m_i[2] = {-3.0e38f, -3.0e38f};
    float l_i[2] = {0.f, 0.f};

    for (int m0 = 0; m0 < N_; m0 += 32) {
        __syncthreads();
        // commit prefetched tile to LDS
#pragma unroll
        for (int s = 0; s < 2; ++s) {
            int idx = tid + 256 * s;
            int r = idx >> 4, c = idx & 15;
            *(uint4*)&gS[r * 136 + c * 8] = gR[s];
        }
#pragma unroll
        for (int s = 0; s < 8; ++s) {
            int idx = tid + 256 * s;
            int rr = idx >> 3, p = idx & 7;
            *(uint2*)&xTs[rr * 40 + p * 4] = xR[s];
        }
        __syncthreads();
        if (m0 + 32 < N_) AT_LOAD_TILE(m0 + 32)

        // ---- QK: S^T[j][i], A=g (m=j), B=f (n=i) ----
        floatx4 sc[2][2];
#pragma unroll
        for (int jt = 0; jt < 2; ++jt)
#pragma unroll
            for (int it = 0; it < 2; ++it)
                sc[jt][it] = (floatx4){0.f, 0.f, 0.f, 0.f};
#pragma unroll
        for (int kc = 0; kc < 4; ++kc) {
            half8v ga0 = *(const half8v*)&gS[(l16     ) * 136 + kc * 32 + quad * 8];
            half8v ga1 = *(const half8v*)&gS[(l16 + 16) * 136 + kc * 32 + quad * 8];
            sc[0][0] = mfma_16x16x32(ga0, fb[0][kc], sc[0][0]);
            sc[0][1] = mfma_16x16x32(ga0, fb[1][kc], sc[0][1]);
            sc[1][0] = mfma_16x16x32(ga1, fb[0][kc], sc[1][0]);
            sc[1][1] = mfma_16x16x32(ga1, fb[1][kc], sc[1][1]);
        }

        // ---- lazy online softmax (state per query i = l16, per i-tile) ----
        float tm[2];
#pragma unroll
        for (int it = 0; it < 2; ++it) {
            float t0 = fmaxf(fmaxf(sc[0][it][0], sc[0][it][1]),
                             fmaxf(sc[0][it][2], sc[0][it][3]));
            float t1 = fmaxf(fmaxf(sc[1][it][0], sc[1][it][1]),
                             fmaxf(sc[1][it][2], sc[1][it][3]));
            float tv = fmaxf(t0, t1);
            tv = fmaxf(tv, __shfl_xor(tv, 16));
            tv = fmaxf(tv, __shfl_xor(tv, 32));
            tm[it] = tv;
        }
        bool needl = (tm[0] > m_i[0] + 8.0f) || (tm[1] > m_i[1] + 8.0f);
        if (__any(needl)) {
            float alpha[2];
#pragma unroll
            for (int it = 0; it < 2; ++it) {
                float mnew = fmaxf(m_i[it], tm[it]);
                alpha[it] = __expf(m_i[it] - mnew);   // first tile: exp(-inf)=0
                m_i[it] = mnew;
                l_i[it] *= alpha[it];
            }
            float ar[2][4];
#pragma unroll
            for (int it = 0; it < 2; ++it)
#pragma unroll
                for (int r = 0; r < 4; ++r)
                    ar[it][r] = __shfl(alpha[it], quad * 4 + r);
#pragma unroll
            for (int it = 0; it < 2; ++it)
#pragma unroll
                for (int dt = 0; dt < 16; ++dt)
#pragma unroll
                    for (int r = 0; r < 4; ++r)
                        acc[it][dt][r] *= ar[it][r];
        }

        half4v pa[2][2];     // pa[jt][it]: PV A-frag (k = quad*4 + reg)
#pragma unroll
        for (int it = 0; it < 2; ++it) {
            float rs = 0.f;
#pragma unroll
            for (int jt = 0; jt < 2; ++jt) {
                float p0 = __expf(sc[jt][it][0] - m_i[it]);
                float p1 = __expf(sc[jt][it][1] - m_i[it]);
                float p2 = __expf(sc[jt][it][2] - m_i[it]);
                float p3 = __expf(sc[jt][it][3] - m_i[it]);
                rs += (p0 + p1) + (p2 + p3);
                pa[jt][it] = (half4v){(_Float16)p0, (_Float16)p1,
                                      (_Float16)p2, (_Float16)p3};
            }
            rs += __shfl_xor(rs, 16);
            rs += __shfl_xor(rs, 32);
            l_i[it] += rs;
        }

        // ---- PV: one b128 per dt gives both K=16 B-frags (permuted rows) ----
#pragma unroll
        for (int dt = 0; dt < 16; ++dt) {
            half8v xb = *(const half8v*)&xTs[(dt * 16 + l16) * 40 + quad * 8];
            half4v xb0 = __builtin_shufflevector(xb, xb, 0, 1, 2, 3);
            half4v xb1 = __builtin_shufflevector(xb, xb, 4, 5, 6, 7);
            acc[0][dt] = mfma_16x16x16(pa[0][0], xb0, acc[0][dt]);
            acc[0][dt] = mfma_16x16x16(pa[1][0], xb1, acc[0][dt]);
            acc[1][dt] = mfma_16x16x16(pa[0][1], xb0, acc[1][dt]);
            acc[1][dt] = mfma_16x16x16(pa[1][1], xb1, acc[1][dt]);
        }
    }

    // ---- epilogue: normalize, residual, store ----
    float linv[2][4];
#pragma unroll
    for (int it = 0; it < 2; ++it)
#pragma unroll
        for (int r = 0; r < 4; ++r)
            linv[it][r] = 1.0f / __shfl(l_i[it], quad * 4 + r);

#pragma unroll
    for (int it = 0; it < 2; ++it)
#pragma unroll
        for (int r = 0; r < 4; ++r) {
            const size_t rowoff =
                ((size_t)(b * N_ + qbase + it * 16 + quad * 4 + r)) * D_ + d0;
#pragma unroll
            for (int dt = 0; dt < 16; ++dt) {
                int col = dt * 16 + l16;
                out[rowoff + col] = fmaf(acc[it][dt][r], linv[it][r], x[rowoff + col]);
            }
        }
}

extern "C" void kernel_launch(void* const* d_in, const int* in_sizes, int n_in,
                              void* d_out, int out_size, void* d_ws, size_t ws_size,
                              hipStream_t stream) {
    const float* x   = (const float*)d_in[0];
    const float* Wf  = (const float*)d_in[1];
    const float* bfv = (const float*)d_in[2];
    const float* Wg  = (const float*)d_in[3];
    const float* bgv = (const float*)d_in[4];
    float* out = (float*)d_out;

    // ws (f16 elements): fh[2.1M] gh[2.1M] xT[16.8M] whT[0.26M]  = 42.5 MB
    _Float16* fh  = (_Float16*)d_ws;
    _Float16* gh  = fh + (size_t)B_ * N_ * A_;
    _Float16* xT  = gh + (size_t)B_ * N_ * A_;
    _Float16* whT = xT + (size_t)B_ * D_ * N_;

    hipLaunchKernelGGL(xpose_kernel, dim3(N_ / 64, D_ / 64, B_), dim3(256), 0, stream,
                       x, xT);
    hipLaunchKernelGGL(wprep_kernel, dim3(D_ / 64, A_ / 64, 2), dim3(256), 0, stream,
                       Wf, Wg, whT);
    hipLaunchKernelGGL(fgmm_kernel, dim3(2, B_ * N_ / 64), dim3(256), 0, stream,
                       x, whT, bfv, bgv, fh, gh);
    hipLaunchKernelGGL(attn_kernel, dim3(D_ / 256, N_ / 128, B_), dim3(256), 0, stream,
                       x, fh, gh, xT, out);
}